// Round 2
// baseline (288.703 us; speedup 1.0000x reference)
//
#include <hip/hip_runtime.h>
#include <hip/hip_bf16.h>

#define B_ 4096
#define N_ 64
#define D_ 128
#define H_ 2
#define M_ 384
#define DK_ 192

// ws float offsets
#define WS_WKEFF 64
#define WS_W1T   1024
#define WS_W2T   66560
#define WS_CTX   82944
#define WS_OUTV  (WS_CTX + B_ * (H_ * M_))
#define WS_R     (WS_OUTV + B_ * M_)
#define WS_TOTAL (WS_R + B_ * M_)

// ---------------------------------------------------------------- mask dtype probe
// flag: 0 = int32 storage, 1 = byte (numpy bool), 2 = float32
__global__ void detect_mask(const void* __restrict__ mask, int* __restrict__ flag) {
    const unsigned int* u = (const unsigned int*)mask;
    bool all01 = true, allf = true;
    for (int i = 0; i < 64; ++i) {
        unsigned int v = u[i];
        if (v != 0u && v != 1u) all01 = false;
        if (v != 0u && v != 0x3f800000u) allf = false;
    }
    *flag = all01 ? 0 : (allf ? 2 : 1);
}

// ---------------------------------------------------------------- prep: wk_eff, W1^T, W2^T
__global__ void prep(const float* __restrict__ Wk, const float* __restrict__ wmap,
                     const float* __restrict__ W1, const float* __restrict__ W2,
                     float* __restrict__ wkeff, float* __restrict__ W1t, float* __restrict__ W2t) {
    int gt = blockIdx.x * blockDim.x + threadIdx.x;
    int stride = gridDim.x * blockDim.x;
    for (int o = gt; o < H_ * M_; o += stride) {
        int h = o / M_, m = o % M_;
        float s = 0.f;
        for (int d = 0; d < DK_; ++d) s += wmap[DK_ + d] * Wk[(size_t)(h * DK_ + d) * M_ + m];
        wkeff[o] = s;
    }
    for (int i = gt; i < (M_ + D_) * D_; i += stride) {   // W1t[k*128+o] = W1[o*512+k]
        int k = i >> 7, o = i & 127;
        W1t[i] = W1[(size_t)o * (M_ + D_) + k];
    }
    for (int i = gt; i < D_ * D_; i += stride) {          // W2t[k*128+o] = W2[o*128+k]
        int k = i >> 7, o = i & 127;
        W2t[i] = W2[(size_t)o * D_ + k];
    }
}

// ---------------------------------------------------------------- fused attention per b
__global__ __launch_bounds__(512) void attn_fused(
    const float* __restrict__ seq, const float* __restrict__ seq_e,
    const float* __restrict__ seq_t, const void* __restrict__ mask,
    const float* __restrict__ wkeff, const int* __restrict__ flagp,
    float* __restrict__ ctx, float* __restrict__ attn_out) {
    __shared__ __hip_bfloat16 skb[N_ * M_];   // 48 KB
    __shared__ float swk[H_ * M_];
    __shared__ float slog[H_ * N_];

    const int b = blockIdx.x;
    const int tid = threadIdx.x;
    const int wave = tid >> 6;
    const int lane = tid & 63;

    // stage k_in = [seq | seq_e | seq_t] as bf16 (f32 in HBM, one read)
    const float* base0 = seq   + (size_t)b * (N_ * D_);
    const float* base1 = seq_e + (size_t)b * (N_ * D_);
    const float* base2 = seq_t + (size_t)b * (N_ * D_);
    const float* bases[3] = {base0, base1, base2};
    for (int t3 = 0; t3 < 3; ++t3) {
        const float4* p = (const float4*)bases[t3];
        for (int idx = tid; idx < (N_ * D_ / 4); idx += 512) {
            float4 v = p[idx];
            int n = idx >> 5;            // 32 float4 per 128-row
            int j = (idx & 31) << 2;
            union { short4 s4; __hip_bfloat16 h[4]; } u;
            u.h[0] = __float2bfloat16(v.x); u.h[1] = __float2bfloat16(v.y);
            u.h[2] = __float2bfloat16(v.z); u.h[3] = __float2bfloat16(v.w);
            *reinterpret_cast<short4*>(&skb[n * M_ + t3 * D_ + j]) = u.s4;
        }
    }
    for (int i = tid; i < H_ * M_; i += 512) swk[i] = wkeff[i];
    __syncthreads();

    // logits: 128 dots (h,n) of length 384; one dot per wave iteration, lanes cover m
    for (int i = 0; i < 16; ++i) {
        int dIdx = wave * 16 + i;                 // 0..127
        int h = dIdx >> 6, n = dIdx & 63;
        const __hip_bfloat16* kr = &skb[n * M_];
        const float* wr = &swk[h * M_];
        float p = 0.f;
        #pragma unroll
        for (int r = 0; r < 6; ++r) {
            int m = lane + (r << 6);
            p += __bfloat162float(kr[m]) * wr[m];
        }
        #pragma unroll
        for (int off = 32; off > 0; off >>= 1) p += __shfl_xor(p, off, 64);
        if (lane == 0) slog[dIdx] = p;
    }
    __syncthreads();

    // mask + softmax: wave0 -> h=0, wave1 -> h=1, lane = n
    if (tid < H_ * N_) {
        int h = wave, n = lane;
        float lg = slog[tid];
        int flag = *flagp;
        int mv;
        if (flag == 0)      mv = ((const int*)mask)[b * N_ + n];
        else if (flag == 1) mv = ((const unsigned char*)mask)[b * N_ + n];
        else                mv = (((const unsigned int*)mask)[b * N_ + n] != 0u) ? 1 : 0;
        if (mv) lg = -INFINITY;
        float mx = lg;
        #pragma unroll
        for (int off = 32; off > 0; off >>= 1) mx = fmaxf(mx, __shfl_xor(mx, off, 64));
        float e = __expf(lg - mx);
        float s = e;
        #pragma unroll
        for (int off = 32; off > 0; off >>= 1) s += __shfl_xor(s, off, 64);
        float a = e / s;
        slog[tid] = a;
        attn_out[((size_t)h * B_ + b) * N_ + n] = a;
    }
    __syncthreads();

    // ctx[h][m] = sum_n attn[h][n] * k_in[n][m]
    for (int o = tid; o < H_ * M_; o += 512) {
        int h = (o >= M_) ? 1 : 0;
        int m = o - h * M_;
        const float* av = &slog[h * N_];
        float acc = 0.f;
        #pragma unroll 8
        for (int n = 0; n < N_; ++n)
            acc += av[n] * __bfloat162float(skb[n * M_ + m]);
        ctx[(size_t)b * (H_ * M_) + o] = acc;
    }
}

// ---------------------------------------------------------------- GEMM: out_v = ctx_h @ Wv_h^T
__global__ __launch_bounds__(256) void gemm_v(
    const float* __restrict__ ctx, const float* __restrict__ Wv, float* __restrict__ outv) {
    __shared__ float sA[16 * 65], sB[16 * 65];
    const int j0 = blockIdx.x * 64;
    const int b0 = blockIdx.y * 64;
    const int aOff = (j0 >= DK_) ? M_ : 0;   // head select
    const int tid = threadIdx.x;
    const int tx = tid & 15, ty = tid >> 4;
    const int li = tid >> 2, lk = (tid & 3) << 2;
    float acc[4][4] = {};
    for (int kk = 0; kk < M_; kk += 16) {
        float4 va = *(const float4*)&ctx[(size_t)(b0 + li) * (H_ * M_) + aOff + kk + lk];
        float4 vb = *(const float4*)&Wv[(size_t)(j0 + li) * M_ + kk + lk];
        sA[(lk + 0) * 65 + li] = va.x; sA[(lk + 1) * 65 + li] = va.y;
        sA[(lk + 2) * 65 + li] = va.z; sA[(lk + 3) * 65 + li] = va.w;
        sB[(lk + 0) * 65 + li] = vb.x; sB[(lk + 1) * 65 + li] = vb.y;
        sB[(lk + 2) * 65 + li] = vb.z; sB[(lk + 3) * 65 + li] = vb.w;
        __syncthreads();
        #pragma unroll
        for (int k = 0; k < 16; ++k) {
            float ar[4], bc[4];
            #pragma unroll
            for (int r = 0; r < 4; ++r) ar[r] = sA[k * 65 + ty * 4 + r];
            #pragma unroll
            for (int c = 0; c < 4; ++c) bc[c] = sB[k * 65 + tx * 4 + c];
            #pragma unroll
            for (int r = 0; r < 4; ++r)
                #pragma unroll
                for (int c = 0; c < 4; ++c) acc[r][c] += ar[r] * bc[c];
        }
        __syncthreads();
    }
    for (int r = 0; r < 4; ++r)
        *(float4*)&outv[(size_t)(b0 + ty * 4 + r) * M_ + j0 + tx * 4] =
            make_float4(acc[r][0], acc[r][1], acc[r][2], acc[r][3]);
}

// ---------------------------------------------------------------- GEMM: fc + leaky + residual
__global__ __launch_bounds__(256) void gemm_fc(
    const float* __restrict__ A, const float* __restrict__ Wfc, const float* __restrict__ bfc,
    const float* __restrict__ src, const float* __restrict__ src_s, const float* __restrict__ src_t,
    float* __restrict__ rws) {
    __shared__ float sA[16 * 65], sB[16 * 65];
    const int j0 = blockIdx.x * 64;
    const int b0 = blockIdx.y * 64;
    const int tid = threadIdx.x;
    const int tx = tid & 15, ty = tid >> 4;
    const int li = tid >> 2, lk = (tid & 3) << 2;
    float acc[4][4] = {};
    for (int kk = 0; kk < M_; kk += 16) {
        float4 va = *(const float4*)&A[(size_t)(b0 + li) * M_ + kk + lk];
        float4 vb = *(const float4*)&Wfc[(size_t)(j0 + li) * M_ + kk + lk];
        sA[(lk + 0) * 65 + li] = va.x; sA[(lk + 1) * 65 + li] = va.y;
        sA[(lk + 2) * 65 + li] = va.z; sA[(lk + 3) * 65 + li] = va.w;
        sB[(lk + 0) * 65 + li] = vb.x; sB[(lk + 1) * 65 + li] = vb.y;
        sB[(lk + 2) * 65 + li] = vb.z; sB[(lk + 3) * 65 + li] = vb.w;
        __syncthreads();
        #pragma unroll
        for (int k = 0; k < 16; ++k) {
            float ar[4], bc[4];
            #pragma unroll
            for (int r = 0; r < 4; ++r) ar[r] = sA[k * 65 + ty * 4 + r];
            #pragma unroll
            for (int c = 0; c < 4; ++c) bc[c] = sB[k * 65 + tx * 4 + c];
            #pragma unroll
            for (int r = 0; r < 4; ++r)
                #pragma unroll
                for (int c = 0; c < 4; ++c) acc[r][c] += ar[r] * bc[c];
        }
        __syncthreads();
    }
    // epilogue: +bfc, leaky(0.2), + q_in residual (tile is head/source uniform: 64 | 128 boundaries)
    const float* qsrc = (j0 < D_) ? src : (j0 < 2 * D_) ? src_s : src_t;
    const int joff = j0 - ((j0 < D_) ? 0 : (j0 < 2 * D_) ? D_ : 2 * D_);
    for (int r = 0; r < 4; ++r) {
        int i = b0 + ty * 4 + r;
        float4 qv = *(const float4*)&qsrc[(size_t)i * D_ + joff + tx * 4];
        float q[4] = {qv.x, qv.y, qv.z, qv.w};
        float res[4];
        #pragma unroll
        for (int c = 0; c < 4; ++c) {
            int j = j0 + tx * 4 + c;
            float t = acc[r][c] + bfc[j];
            t = t > 0.f ? t : 0.2f * t;
            res[c] = t + q[c];
        }
        *(float4*)&rws[(size_t)i * M_ + j0 + tx * 4] = make_float4(res[0], res[1], res[2], res[3]);
    }
}

// ---------------------------------------------------------------- LayerNorm + MLP
__global__ __launch_bounds__(256) void ln_mlp(
    const float* __restrict__ rin, const float* __restrict__ src,
    const float* __restrict__ g, const float* __restrict__ bta,
    const float* __restrict__ W1t, const float* __restrict__ b1,
    const float* __restrict__ W2t, const float* __restrict__ b2,
    float* __restrict__ outp) {
    __shared__ float sz[32 * 385];   // z tile; later aliased as h tile (stride 129)
    const int b0 = blockIdx.x * 32;
    const int tid = threadIdx.x;
    {
        const int row = tid >> 3, part = tid & 7;   // 8 threads per row
        const float* rr = &rin[(size_t)(b0 + row) * M_];
        float s = 0.f, sq = 0.f;
        #pragma unroll 8
        for (int i = 0; i < 48; ++i) { float v = rr[part + (i << 3)]; s += v; sq += v * v; }
        #pragma unroll
        for (int off = 1; off < 8; off <<= 1) { s += __shfl_xor(s, off, 64); sq += __shfl_xor(sq, off, 64); }
        float mu = s * (1.f / 384.f);
        float var = sq * (1.f / 384.f) - mu * mu;
        float rs = rsqrtf(var + 1e-5f);
        for (int i = 0; i < 48; ++i) {
            int k = part + (i << 3);
            sz[row * 385 + k] = (rr[k] - mu) * rs * g[k] + bta[k];
        }
    }
    __syncthreads();
    const int tx = tid & 15, ty = tid >> 4;   // cols o = tx*8+c, rows r2 = ty*2+rr
    float acc[2][8] = {};
    for (int k = 0; k < M_; ++k) {
        float a0 = sz[(ty * 2 + 0) * 385 + k];
        float a1 = sz[(ty * 2 + 1) * 385 + k];
        float4 w0 = *(const float4*)&W1t[k * D_ + tx * 8];
        float4 w1 = *(const float4*)&W1t[k * D_ + tx * 8 + 4];
        float w[8] = {w0.x, w0.y, w0.z, w0.w, w1.x, w1.y, w1.z, w1.w};
        #pragma unroll
        for (int c = 0; c < 8; ++c) { acc[0][c] += a0 * w[c]; acc[1][c] += a1 * w[c]; }
    }
    for (int k = M_; k < M_ + D_; ++k) {
        float a0 = src[(size_t)(b0 + ty * 2 + 0) * D_ + (k - M_)];
        float a1 = src[(size_t)(b0 + ty * 2 + 1) * D_ + (k - M_)];
        float4 w0 = *(const float4*)&W1t[k * D_ + tx * 8];
        float4 w1 = *(const float4*)&W1t[k * D_ + tx * 8 + 4];
        float w[8] = {w0.x, w0.y, w0.z, w0.w, w1.x, w1.y, w1.z, w1.w};
        #pragma unroll
        for (int c = 0; c < 8; ++c) { acc[0][c] += a0 * w[c]; acc[1][c] += a1 * w[c]; }
    }
    __syncthreads();
    float* sh = sz;   // alias (all sz reads complete)
    #pragma unroll
    for (int rr2 = 0; rr2 < 2; ++rr2)
        #pragma unroll
        for (int c = 0; c < 8; ++c) {
            int r2 = ty * 2 + rr2, o = tx * 8 + c;
            float t = acc[rr2][c] + b1[o];
            sh[r2 * 129 + o] = t > 0.f ? t : 0.f;
        }
    __syncthreads();
    float acc2[2][8] = {};
    for (int k = 0; k < D_; ++k) {
        float a0 = sh[(ty * 2 + 0) * 129 + k];
        float a1 = sh[(ty * 2 + 1) * 129 + k];
        float4 w0 = *(const float4*)&W2t[k * D_ + tx * 8];
        float4 w1 = *(const float4*)&W2t[k * D_ + tx * 8 + 4];
        float w[8] = {w0.x, w0.y, w0.z, w0.w, w1.x, w1.y, w1.z, w1.w};
        #pragma unroll
        for (int c = 0; c < 8; ++c) { acc2[0][c] += a0 * w[c]; acc2[1][c] += a1 * w[c]; }
    }
    #pragma unroll
    for (int rr2 = 0; rr2 < 2; ++rr2) {
        int r2 = b0 + ty * 2 + rr2;
        float4 o0 = make_float4(acc2[rr2][0] + b2[tx * 8 + 0], acc2[rr2][1] + b2[tx * 8 + 1],
                                acc2[rr2][2] + b2[tx * 8 + 2], acc2[rr2][3] + b2[tx * 8 + 3]);
        float4 o1 = make_float4(acc2[rr2][4] + b2[tx * 8 + 4], acc2[rr2][5] + b2[tx * 8 + 5],
                                acc2[rr2][6] + b2[tx * 8 + 6], acc2[rr2][7] + b2[tx * 8 + 7]);
        *(float4*)&outp[(size_t)r2 * D_ + tx * 8] = o0;
        *(float4*)&outp[(size_t)r2 * D_ + tx * 8 + 4] = o1;
    }
}

// ---------------------------------------------------------------- launcher
extern "C" void kernel_launch(void* const* d_in, const int* in_sizes, int n_in,
                              void* d_out, int out_size, void* d_ws, size_t ws_size,
                              hipStream_t stream) {
    (void)in_sizes; (void)n_in; (void)out_size;
    const float* src   = (const float*)d_in[0];
    const float* src_t = (const float*)d_in[1];
    const float* src_s = (const float*)d_in[2];
    const float* seq   = (const float*)d_in[3];
    const float* seq_t = (const float*)d_in[4];
    const float* seq_e = (const float*)d_in[5];
    const void*  mask  = d_in[6];
    // d_in[7] = Wq: unused (cancels in softmax)
    const float* Wk    = (const float*)d_in[8];
    const float* Wv    = (const float*)d_in[9];
    const float* wmap  = (const float*)d_in[10];
    const float* Wfc   = (const float*)d_in[11];
    const float* bfc   = (const float*)d_in[12];
    const float* ln_g  = (const float*)d_in[13];
    const float* ln_b  = (const float*)d_in[14];
    const float* W1    = (const float*)d_in[15];
    const float* b1    = (const float*)d_in[16];
    const float* W2    = (const float*)d_in[17];
    const float* b2    = (const float*)d_in[18];

    if (ws_size < (size_t)WS_TOTAL * sizeof(float)) return;
    float* wsf   = (float*)d_ws;
    int*   flagp = (int*)d_ws;           // ws[0..15] reserved
    float* wkeff = wsf + WS_WKEFF;
    float* W1t   = wsf + WS_W1T;
    float* W2t   = wsf + WS_W2T;
    float* ctx   = wsf + WS_CTX;
    float* outv  = wsf + WS_OUTV;
    float* rws   = wsf + WS_R;
    float* outp     = (float*)d_out;
    float* attn_out = outp + (size_t)B_ * D_;

    detect_mask<<<1, 1, 0, stream>>>(mask, flagp);
    prep<<<48, 256, 0, stream>>>(Wk, wmap, W1, W2, wkeff, W1t, W2t);
    attn_fused<<<B_, 512, 0, stream>>>(seq, seq_e, seq_t, mask, wkeff, flagp, ctx, attn_out);
    gemm_v<<<dim3(6, 64), 256, 0, stream>>>(ctx, Wv, outv);
    gemm_fc<<<dim3(6, 64), 256, 0, stream>>>(outv, Wfc, bfc, src, src_s, src_t, rws);
    ln_mlp<<<128, 256, 0, stream>>>(rws, src, ln_g, ln_b, W1t, b1, W2t, b2, outp);
}

// Round 3
// 195.590 us; speedup vs baseline: 1.4761x; 1.4761x over previous
//
#include <hip/hip_runtime.h>
#include <hip/hip_bf16.h>

#define B_ 4096
#define N_ 64
#define D_ 128
#define H_ 2
#define M_ 384
#define DK_ 192

// ws float offsets
#define WS_WKEFF 64
#define WS_W1T   1024
#define WS_W2T   66560
#define WS_CTX   82944
#define WS_OUTV  (WS_CTX + B_ * (H_ * M_))
#define WS_R     (WS_OUTV + B_ * M_)
#define WS_TOTAL (WS_R + B_ * M_)

__device__ __forceinline__ unsigned pk2(float a, float b) {
    __hip_bfloat16 x = __float2bfloat16(a), y = __float2bfloat16(b);
    unsigned short ux = __builtin_bit_cast(unsigned short, x);
    unsigned short uy = __builtin_bit_cast(unsigned short, y);
    return (unsigned)ux | ((unsigned)uy << 16);
}
__device__ __forceinline__ float bflo(int v) { return __builtin_bit_cast(float, (unsigned)v << 16); }
__device__ __forceinline__ float bfhi(int v) { return __builtin_bit_cast(float, (unsigned)v & 0xffff0000u); }

// ---------------------------------------------------------------- mask dtype probe
__global__ void detect_mask(const void* __restrict__ mask, int* __restrict__ flag) {
    const unsigned int* u = (const unsigned int*)mask;
    bool all01 = true, allf = true;
    for (int i = 0; i < 64; ++i) {
        unsigned int v = u[i];
        if (v != 0u && v != 1u) all01 = false;
        if (v != 0u && v != 0x3f800000u) allf = false;
    }
    *flag = all01 ? 0 : (allf ? 2 : 1);
}

// ---------------------------------------------------------------- prep: wk_eff (wave-parallel), W1^T, W2^T
__global__ __launch_bounds__(256) void prep2(
    const float* __restrict__ Wk, const float* __restrict__ wmap,
    const float* __restrict__ W1, const float* __restrict__ W2,
    float* __restrict__ wkeff, float* __restrict__ W1t, float* __restrict__ W2t) {
    const int tid = threadIdx.x;
    const int lane = tid & 63, wave = tid >> 6;
    const int gw = blockIdx.x * 4 + wave;
    if (gw < H_ * M_) {
        const int h = gw / M_, m = gw - h * M_;
        float s = 0.f;
        #pragma unroll
        for (int i = 0; i < 3; ++i) {
            int d = lane + i * 64;
            s += wmap[DK_ + d] * Wk[(size_t)(h * DK_ + d) * M_ + m];
        }
        #pragma unroll
        for (int off = 1; off < 64; off <<= 1) s += __shfl_xor(s, off, 64);
        if (lane == 0) wkeff[gw] = s;
    }
    const int gt = blockIdx.x * 256 + tid;
    const int stride = gridDim.x * 256;
    for (int i = gt; i < (M_ + D_) * D_; i += stride) {
        int k = i >> 7, o = i & 127;
        W1t[i] = W1[(size_t)o * (M_ + D_) + k];
    }
    for (int i = gt; i < D_ * D_; i += stride) {
        int k = i >> 7, o = i & 127;
        W2t[i] = W2[(size_t)o * D_ + k];
    }
}

// ---------------------------------------------------------------- fused attention per b (DS-lean v2)
#define PADROW 392
__global__ __launch_bounds__(512) void attn_fused(
    const float* __restrict__ seq, const float* __restrict__ seq_e,
    const float* __restrict__ seq_t, const void* __restrict__ mask,
    const float* __restrict__ wkeff, const int* __restrict__ flagp,
    float* __restrict__ ctx, float* __restrict__ attn_out) {
    __shared__ __hip_bfloat16 skb[N_ * PADROW];   // 50176 B
    __shared__ float slog[H_ * N_];

    const int b = blockIdx.x;
    const int tid = threadIdx.x;
    const int lane = tid & 63;
    const int j8 = tid & 15;

    // wkeff weights in registers: wr[h][t][j] = wkeff[h*384 + t*128 + j8*8 + j]
    float wr[2][3][8];
    #pragma unroll
    for (int h = 0; h < 2; ++h)
        #pragma unroll
        for (int t = 0; t < 3; ++t) {
            float4 wa = *(const float4*)&wkeff[h * M_ + t * 128 + j8 * 8];
            float4 wb = *(const float4*)&wkeff[h * M_ + t * 128 + j8 * 8 + 4];
            wr[h][t][0] = wa.x; wr[h][t][1] = wa.y; wr[h][t][2] = wa.z; wr[h][t][3] = wa.w;
            wr[h][t][4] = wb.x; wr[h][t][5] = wb.y; wr[h][t][6] = wb.z; wr[h][t][7] = wb.w;
        }

    const float* base0 = seq   + (size_t)b * (N_ * D_);
    const float* base1 = seq_e + (size_t)b * (N_ * D_);
    const float* base2 = seq_t + (size_t)b * (N_ * D_);

    // staging (f32 -> bf16 LDS, b128 writes) fused with logit partial dots
    #pragma unroll
    for (int k2 = 0; k2 < 2; ++k2) {
        const int idx8 = k2 * 512 + tid;     // float8-chunk index, 1024 per array
        const int n = idx8 >> 4;             // row 0..63
        float a0 = 0.f, a1 = 0.f;
        #pragma unroll
        for (int t = 0; t < 3; ++t) {
            const float* bp = (t == 0) ? base0 : (t == 1) ? base1 : base2;
            float4 v0 = *(const float4*)&bp[idx8 * 8];
            float4 v1 = *(const float4*)&bp[idx8 * 8 + 4];
            a0 += v0.x * wr[0][t][0] + v0.y * wr[0][t][1] + v0.z * wr[0][t][2] + v0.w * wr[0][t][3]
                + v1.x * wr[0][t][4] + v1.y * wr[0][t][5] + v1.z * wr[0][t][6] + v1.w * wr[0][t][7];
            a1 += v0.x * wr[1][t][0] + v0.y * wr[1][t][1] + v0.z * wr[1][t][2] + v0.w * wr[1][t][3]
                + v1.x * wr[1][t][4] + v1.y * wr[1][t][5] + v1.z * wr[1][t][6] + v1.w * wr[1][t][7];
            int4 pk;
            pk.x = (int)pk2(v0.x, v0.y); pk.y = (int)pk2(v0.z, v0.w);
            pk.z = (int)pk2(v1.x, v1.y); pk.w = (int)pk2(v1.z, v1.w);
            *(int4*)&skb[n * PADROW + t * 128 + j8 * 8] = pk;
        }
        // reduce across the 16-lane group sharing row n
        #pragma unroll
        for (int off = 1; off < 16; off <<= 1) {
            a0 += __shfl_xor(a0, off, 64);
            a1 += __shfl_xor(a1, off, 64);
        }
        if ((lane & 15) == 0) { slog[n] = a0; slog[64 + n] = a1; }
    }
    __syncthreads();

    // mask + softmax: wave0 -> h=0, wave1 -> h=1, lane = n
    if (tid < H_ * N_) {
        const int h = tid >> 6, n = tid & 63;
        float lg = slog[tid];
        const int flag = *flagp;
        int mv;
        if (flag == 0)      mv = ((const int*)mask)[b * N_ + n];
        else if (flag == 1) mv = ((const unsigned char*)mask)[b * N_ + n];
        else                mv = (((const unsigned int*)mask)[b * N_ + n] != 0u) ? 1 : 0;
        if (mv) lg = -INFINITY;
        float mx = lg;
        #pragma unroll
        for (int off = 32; off > 0; off >>= 1) mx = fmaxf(mx, __shfl_xor(mx, off, 64));
        float e = __expf(lg - mx);
        float s = e;
        #pragma unroll
        for (int off = 32; off > 0; off >>= 1) s += __shfl_xor(s, off, 64);
        float a = e / s;
        slog[tid] = a;
        attn_out[((size_t)h * B_ + b) * N_ + n] = a;
    }
    __syncthreads();

    // ctx[h][m8*8..+8] = sum_n attn[h][n] * k_in[n][m], vectorized bf16x8, 4-way n-split
    if (tid < 384) {
        const int u = tid >> 2, q = tid & 3;
        const int h = (u >= 48) ? 1 : 0;
        const int m8 = u - h * 48;
        const float* ar = &slog[h * 64];
        float acc[8] = {};
        #pragma unroll
        for (int i = 0; i < 16; ++i) {
            const int n = q * 16 + ((i + q * 4) & 15);   // bank skew across q
            const float a = ar[n];
            int4 kv = *(const int4*)&skb[n * PADROW + m8 * 8];
            acc[0] += a * bflo(kv.x); acc[1] += a * bfhi(kv.x);
            acc[2] += a * bflo(kv.y); acc[3] += a * bfhi(kv.y);
            acc[4] += a * bflo(kv.z); acc[5] += a * bfhi(kv.z);
            acc[6] += a * bflo(kv.w); acc[7] += a * bfhi(kv.w);
        }
        #pragma unroll
        for (int off = 1; off < 4; off <<= 1)
            #pragma unroll
            for (int j = 0; j < 8; ++j) acc[j] += __shfl_xor(acc[j], off, 64);
        if (q == 0) {
            float4 o0 = make_float4(acc[0], acc[1], acc[2], acc[3]);
            float4 o1 = make_float4(acc[4], acc[5], acc[6], acc[7]);
            *(float4*)&ctx[(size_t)b * (H_ * M_) + h * M_ + m8 * 8] = o0;
            *(float4*)&ctx[(size_t)b * (H_ * M_) + h * M_ + m8 * 8 + 4] = o1;
        }
    }
}

// ---------------------------------------------------------------- GEMM: out_v = ctx_h @ Wv_h^T  (BK=32)
__global__ __launch_bounds__(256) void gemm_v(
    const float* __restrict__ ctx, const float* __restrict__ Wv, float* __restrict__ outv) {
    __shared__ float sA[32 * 68], sB[32 * 68];
    const int j0 = blockIdx.x * 64;
    const int b0 = blockIdx.y * 64;
    const int aOff = (j0 >= DK_) ? M_ : 0;
    const int tid = threadIdx.x;
    const int tx = tid & 15, ty = tid >> 4;
    const int lr = tid >> 2, lc = (tid & 3) * 8;
    float acc[4][4] = {};
    for (int kk = 0; kk < M_; kk += 32) {
        float4 va  = *(const float4*)&ctx[(size_t)(b0 + lr) * (H_ * M_) + aOff + kk + lc];
        float4 va2 = *(const float4*)&ctx[(size_t)(b0 + lr) * (H_ * M_) + aOff + kk + lc + 4];
        float4 vb  = *(const float4*)&Wv[(size_t)(j0 + lr) * M_ + kk + lc];
        float4 vb2 = *(const float4*)&Wv[(size_t)(j0 + lr) * M_ + kk + lc + 4];
        __syncthreads();
        sA[(lc + 0) * 68 + lr] = va.x;  sA[(lc + 1) * 68 + lr] = va.y;
        sA[(lc + 2) * 68 + lr] = va.z;  sA[(lc + 3) * 68 + lr] = va.w;
        sA[(lc + 4) * 68 + lr] = va2.x; sA[(lc + 5) * 68 + lr] = va2.y;
        sA[(lc + 6) * 68 + lr] = va2.z; sA[(lc + 7) * 68 + lr] = va2.w;
        sB[(lc + 0) * 68 + lr] = vb.x;  sB[(lc + 1) * 68 + lr] = vb.y;
        sB[(lc + 2) * 68 + lr] = vb.z;  sB[(lc + 3) * 68 + lr] = vb.w;
        sB[(lc + 4) * 68 + lr] = vb2.x; sB[(lc + 5) * 68 + lr] = vb2.y;
        sB[(lc + 6) * 68 + lr] = vb2.z; sB[(lc + 7) * 68 + lr] = vb2.w;
        __syncthreads();
        #pragma unroll
        for (int k = 0; k < 32; ++k) {
            float a[4], bb[4];
            *(float4*)a  = *(const float4*)&sA[k * 68 + ty * 4];
            *(float4*)bb = *(const float4*)&sB[k * 68 + tx * 4];
            #pragma unroll
            for (int r = 0; r < 4; ++r)
                #pragma unroll
                for (int c = 0; c < 4; ++c) acc[r][c] += a[r] * bb[c];
        }
    }
    #pragma unroll
    for (int r = 0; r < 4; ++r)
        *(float4*)&outv[(size_t)(b0 + ty * 4 + r) * M_ + j0 + tx * 4] =
            make_float4(acc[r][0], acc[r][1], acc[r][2], acc[r][3]);
}

// ---------------------------------------------------------------- GEMM: fc + leaky + residual (BK=32)
__global__ __launch_bounds__(256) void gemm_fc(
    const float* __restrict__ A, const float* __restrict__ Wfc, const float* __restrict__ bfc,
    const float* __restrict__ src, const float* __restrict__ src_s, const float* __restrict__ src_t,
    float* __restrict__ rws) {
    __shared__ float sA[32 * 68], sB[32 * 68];
    const int j0 = blockIdx.x * 64;
    const int b0 = blockIdx.y * 64;
    const int tid = threadIdx.x;
    const int tx = tid & 15, ty = tid >> 4;
    const int lr = tid >> 2, lc = (tid & 3) * 8;
    float acc[4][4] = {};
    for (int kk = 0; kk < M_; kk += 32) {
        float4 va  = *(const float4*)&A[(size_t)(b0 + lr) * M_ + kk + lc];
        float4 va2 = *(const float4*)&A[(size_t)(b0 + lr) * M_ + kk + lc + 4];
        float4 vb  = *(const float4*)&Wfc[(size_t)(j0 + lr) * M_ + kk + lc];
        float4 vb2 = *(const float4*)&Wfc[(size_t)(j0 + lr) * M_ + kk + lc + 4];
        __syncthreads();
        sA[(lc + 0) * 68 + lr] = va.x;  sA[(lc + 1) * 68 + lr] = va.y;
        sA[(lc + 2) * 68 + lr] = va.z;  sA[(lc + 3) * 68 + lr] = va.w;
        sA[(lc + 4) * 68 + lr] = va2.x; sA[(lc + 5) * 68 + lr] = va2.y;
        sA[(lc + 6) * 68 + lr] = va2.z; sA[(lc + 7) * 68 + lr] = va2.w;
        sB[(lc + 0) * 68 + lr] = vb.x;  sB[(lc + 1) * 68 + lr] = vb.y;
        sB[(lc + 2) * 68 + lr] = vb.z;  sB[(lc + 3) * 68 + lr] = vb.w;
        sB[(lc + 4) * 68 + lr] = vb2.x; sB[(lc + 5) * 68 + lr] = vb2.y;
        sB[(lc + 6) * 68 + lr] = vb2.z; sB[(lc + 7) * 68 + lr] = vb2.w;
        __syncthreads();
        #pragma unroll
        for (int k = 0; k < 32; ++k) {
            float a[4], bb[4];
            *(float4*)a  = *(const float4*)&sA[k * 68 + ty * 4];
            *(float4*)bb = *(const float4*)&sB[k * 68 + tx * 4];
            #pragma unroll
            for (int r = 0; r < 4; ++r)
                #pragma unroll
                for (int c = 0; c < 4; ++c) acc[r][c] += a[r] * bb[c];
        }
    }
    const float* qsrc = (j0 < D_) ? src : (j0 < 2 * D_) ? src_s : src_t;
    const int joff = j0 % D_;
    #pragma unroll
    for (int r = 0; r < 4; ++r) {
        int i = b0 + ty * 4 + r;
        float4 qv = *(const float4*)&qsrc[(size_t)i * D_ + joff + tx * 4];
        float q[4] = {qv.x, qv.y, qv.z, qv.w};
        float res[4];
        #pragma unroll
        for (int c = 0; c < 4; ++c) {
            int j = j0 + tx * 4 + c;
            float t = acc[r][c] + bfc[j];
            t = t > 0.f ? t : 0.2f * t;
            res[c] = t + q[c];
        }
        *(float4*)&rws[(size_t)i * M_ + j0 + tx * 4] = make_float4(res[0], res[1], res[2], res[3]);
    }
}

// ---------------------------------------------------------------- LayerNorm + MLP (8 rows/block, 512 blocks)
__global__ __launch_bounds__(256) void ln_mlp(
    const float* __restrict__ rin, const float* __restrict__ src,
    const float* __restrict__ g, const float* __restrict__ bta,
    const float* __restrict__ W1t, const float* __restrict__ b1,
    const float* __restrict__ W2t, const float* __restrict__ b2,
    float* __restrict__ outp) {
    __shared__ float sa[8 * 520];   // [z(384) | src(128)] per row, padded
    __shared__ float sh[8 * 132];
    const int b0 = blockIdx.x * 8;
    const int tid = threadIdx.x;
    const int row = tid >> 5, part = tid & 31;
    const size_t gr = (size_t)(b0 + row);
    {
        const float* rr = &rin[gr * M_];
        float4 v[3];
        float s = 0.f, sq = 0.f;
        #pragma unroll
        for (int i = 0; i < 3; ++i) {
            v[i] = *(const float4*)&rr[(part + i * 32) * 4];
            s  += v[i].x + v[i].y + v[i].z + v[i].w;
            sq += v[i].x * v[i].x + v[i].y * v[i].y + v[i].z * v[i].z + v[i].w * v[i].w;
        }
        #pragma unroll
        for (int off = 1; off < 32; off <<= 1) {
            s += __shfl_xor(s, off, 64); sq += __shfl_xor(sq, off, 64);
        }
        float mu = s * (1.f / 384.f);
        float rs = rsqrtf(sq * (1.f / 384.f) - mu * mu + 1e-5f);
        #pragma unroll
        for (int i = 0; i < 3; ++i) {
            int k = (part + i * 32) * 4;
            float4 g4 = *(const float4*)&g[k];
            float4 b4 = *(const float4*)&bta[k];
            float4 z;
            z.x = (v[i].x - mu) * rs * g4.x + b4.x;
            z.y = (v[i].y - mu) * rs * g4.y + b4.y;
            z.z = (v[i].z - mu) * rs * g4.z + b4.z;
            z.w = (v[i].w - mu) * rs * g4.w + b4.w;
            *(float4*)&sa[row * 520 + k] = z;
        }
        *(float4*)&sa[row * 520 + M_ + part * 4] = *(const float4*)&src[gr * D_ + part * 4];
    }
    __syncthreads();
    const int c4 = part * 4;
    float acc[4] = {};
    const float* ar = &sa[row * 520];
    #pragma unroll 4
    for (int k4 = 0; k4 < 128; ++k4) {
        float4 a4 = *(const float4*)&ar[k4 * 4];
        #pragma unroll
        for (int j = 0; j < 4; ++j) {
            int k = k4 * 4 + j;
            float a = (j == 0) ? a4.x : (j == 1) ? a4.y : (j == 2) ? a4.z : a4.w;
            float4 w = *(const float4*)&W1t[k * D_ + c4];
            acc[0] += a * w.x; acc[1] += a * w.y; acc[2] += a * w.z; acc[3] += a * w.w;
        }
    }
    {
        float4 bb = *(const float4*)&b1[c4];
        float4 hh;
        hh.x = fmaxf(acc[0] + bb.x, 0.f);
        hh.y = fmaxf(acc[1] + bb.y, 0.f);
        hh.z = fmaxf(acc[2] + bb.z, 0.f);
        hh.w = fmaxf(acc[3] + bb.w, 0.f);
        *(float4*)&sh[row * 132 + c4] = hh;
    }
    __syncthreads();
    float acc2[4] = {};
    const float* hr = &sh[row * 132];
    #pragma unroll 4
    for (int k4 = 0; k4 < 32; ++k4) {
        float4 a4 = *(const float4*)&hr[k4 * 4];
        #pragma unroll
        for (int j = 0; j < 4; ++j) {
            int k = k4 * 4 + j;
            float a = (j == 0) ? a4.x : (j == 1) ? a4.y : (j == 2) ? a4.z : a4.w;
            float4 w = *(const float4*)&W2t[k * D_ + c4];
            acc2[0] += a * w.x; acc2[1] += a * w.y; acc2[2] += a * w.z; acc2[3] += a * w.w;
        }
    }
    float4 bb2 = *(const float4*)&b2[c4];
    float4 oo = make_float4(acc2[0] + bb2.x, acc2[1] + bb2.y, acc2[2] + bb2.z, acc2[3] + bb2.w);
    *(float4*)&outp[gr * D_ + c4] = oo;
}

// ---------------------------------------------------------------- launcher
extern "C" void kernel_launch(void* const* d_in, const int* in_sizes, int n_in,
                              void* d_out, int out_size, void* d_ws, size_t ws_size,
                              hipStream_t stream) {
    (void)in_sizes; (void)n_in; (void)out_size;
    const float* src   = (const float*)d_in[0];
    const float* src_t = (const float*)d_in[1];
    const float* src_s = (const float*)d_in[2];
    const float* seq   = (const float*)d_in[3];
    const float* seq_t = (const float*)d_in[4];
    const float* seq_e = (const float*)d_in[5];
    const void*  mask  = d_in[6];
    // d_in[7] = Wq: unused (cancels in softmax)
    const float* Wk    = (const float*)d_in[8];
    const float* Wv    = (const float*)d_in[9];
    const float* wmap  = (const float*)d_in[10];
    const float* Wfc   = (const float*)d_in[11];
    const float* bfc   = (const float*)d_in[12];
    const float* ln_g  = (const float*)d_in[13];
    const float* ln_b  = (const float*)d_in[14];
    const float* W1    = (const float*)d_in[15];
    const float* b1    = (const float*)d_in[16];
    const float* W2    = (const float*)d_in[17];
    const float* b2    = (const float*)d_in[18];

    if (ws_size < (size_t)WS_TOTAL * sizeof(float)) return;
    float* wsf   = (float*)d_ws;
    int*   flagp = (int*)d_ws;           // ws[0..15] reserved
    float* wkeff = wsf + WS_WKEFF;
    float* W1t   = wsf + WS_W1T;
    float* W2t   = wsf + WS_W2T;
    float* ctx   = wsf + WS_CTX;
    float* outv  = wsf + WS_OUTV;
    float* rws   = wsf + WS_R;
    float* outp     = (float*)d_out;
    float* attn_out = outp + (size_t)B_ * D_;

    detect_mask<<<1, 1, 0, stream>>>(mask, flagp);
    prep2<<<256, 256, 0, stream>>>(Wk, wmap, W1, W2, wkeff, W1t, W2t);
    attn_fused<<<B_, 512, 0, stream>>>(seq, seq_e, seq_t, mask, wkeff, flagp, ctx, attn_out);
    gemm_v<<<dim3(6, 64), 256, 0, stream>>>(ctx, Wv, outv);
    gemm_fc<<<dim3(6, 64), 256, 0, stream>>>(outv, Wfc, bfc, src, src_s, src_t, rws);
    ln_mlp<<<512, 256, 0, stream>>>(rws, src, ln_g, ln_b, W1t, b1, W2t, b2, outp);
}